// Round 9
// baseline (2406601.367 us; speedup 1.0000x reference)
//
#include <hip/hip_runtime.h>

// NeuralODESIR round 9: lane-pair split + all-f64 weights in LDS.
// r8 datum: f32 weights fix delivery (FETCH 73MB->5.4MB, VALUBusy 66%) but
// cvt-per-MAC (~65k cy/eval) makes it a net loss. Each weight is used once
// per eval per thread -> cvt tax is structural. f64 weights required.
// r7 datum: f64-LDS weights + one-traj-per-thread blows the 256-reg cap.
// Fix: TWO lanes per trajectory (pair via shfl_xor 1):
//   - lane owns half the L2 k's (8 tiles of 8) and half of acc3 (f64[32],
//     64 regs instead of 128) -> ~200 regs total, real slack.
//   - h2 tiles exchanged in-register (8 f64 shfl per tile); L4 partials
//     combined by shfl-add (a+b==b+a bit-exact -> lanes keep identical
//     RK4 state, no divergence).
//   - all 17155 params f64 in LDS (137KB <= 160KB), staged once per block;
//     reads are <=2-address broadcasts (free). No cvt, no SMEM stall.
// Geometry: 512-thr blocks (8 waves/CU = 2/SIMD), grid = 2*B/512 = 512.
// Numerics unchanged (exact f64 MACs, fp32 tanhf, f64 RK4) -> floor 0.01953125.

#define oW1T 0                    // [64][5]   W1 transposed
#define oB1  320                  // [64]
#define oW2L 384                  // [16 tiles][64 i][8 q] = W2[i][c*8+q]
#define oB2  8576                 // [128]
#define oW3L 8704                 // [(row)(2 jh)][32] ; row = c*8+k2
#define oB3  16896                // [64]
#define oW4  16960                // [64][3]
#define oB4  17152                // [3]
#define NTOT 17155
#define LDS_BYTES (NTOT * 8)      // 137240

__device__ __forceinline__ void store_softmax(float* __restrict__ out, size_t base,
                                              float a, float b, float c) {
    float m  = fmaxf(a, fmaxf(b, c));
    float e0 = expf(a - m);
    float e1 = expf(b - m);
    float e2 = expf(c - m);
    float s  = e0 + e1 + e2;
    out[base + 0] = e0 / s;
    out[base + 1] = e1 / s;
    out[base + 2] = e2 / s;
}

__global__ __launch_bounds__(512, 2) void sir_rk4_kernel(
    const float* __restrict__ y0,   const float* __restrict__ tspan,
    const float* __restrict__ beta, const float* __restrict__ gamma,
    const double* __restrict__ P,
    float* __restrict__ out, int B, int T)
{
    extern __shared__ double WL[];   // all params, f64, 137240 B

    // one-time cooperative stage (before any early return: all threads sync)
    for (int i = threadIdx.x; i < NTOT; i += 512)
        WL[i] = P[i];
    __syncthreads();

    const int gtid = blockIdx.x * 512 + threadIdx.x;
    const int traj = gtid >> 1;      // 2 lanes per trajectory
    const int h    = gtid & 1;       // 0: k-tiles 0-7 & j 0-31 ; 1: 8-15 & 32-63
    if (traj >= B) return;

    double ys = (double)y0[traj * 3 + 0];
    double yi = (double)y0[traj * 3 + 1];
    double yr = (double)y0[traj * 3 + 2];
    const double be = (double)beta[traj];
    const double ga = (double)gamma[traj];

    if (h == 0)
        store_softmax(out, (size_t)traj * 3, (float)ys, (float)yi, (float)yr);

    #pragma unroll 1
    for (int t = 0; t < T - 1; ++t) {
        double dt = (double)tspan[t + 1] - (double)tspan[t];

        double ks0 = 0.0, ks1 = 0.0, ks2 = 0.0;
        double zs = ys, zi = yi, zr = yr;

        #pragma unroll 1
        for (int st = 0; st < 4; ++st) {
            // ---- L1: 5 -> 64 (both lanes full h1; LDS broadcast weights) ----
            float h1[64];
            #pragma unroll
            for (int j = 0; j < 64; ++j) {
                const double* w = &WL[oW1T + j * 5];
                double ta = fma(w[0], zs, WL[oB1 + j]);
                double tb = w[2] * zr;
                ta = fma(w[1], zi, ta);
                tb = fma(w[3], be, tb);
                ta = fma(w[4], ga, ta);
                h1[j] = tanhf((float)(ta + tb));
            }

            // my half of the L3 accumulators (j = h*32 .. h*32+31)
            double acc3[32];
            #pragma unroll
            for (int j = 0; j < 32; ++j) acc3[j] = WL[oB3 + h * 32 + j];

            // ---- L2+L3: 64 -> 128 -> 64, pair-split ----
            #pragma unroll 1
            for (int cl = 0; cl < 8; ++cl) {
                const int Town = h * 8 + cl;          // my k-tile (8 k's)
                const int Tpar = (h ^ 1) * 8 + cl;    // partner's k-tile

                // L2 for my tile: h2t[q] = b2 + sum_i W2[i][Town*8+q]*h1[i]
                double h2t[8];
                #pragma unroll
                for (int q = 0; q < 8; ++q) h2t[q] = WL[oB2 + Town * 8 + q];

                const double* wb = &WL[oW2L + Town * 512];
                #pragma unroll
                for (int i = 0; i < 64; ++i) {
                    double hv = (double)h1[i];
                    #pragma unroll
                    for (int q = 0; q < 8; ++q)
                        h2t[q] = fma(wb[i * 8 + q], hv, h2t[q]);
                }

                #pragma unroll
                for (int q = 0; q < 8; ++q)
                    h2t[q] = (double)tanhf((float)h2t[q]);

                // exchange tile activations with partner lane
                double rcv[8];
                #pragma unroll
                for (int q = 0; q < 8; ++q) rcv[q] = __shfl_xor(h2t[q], 1);

                // L3: accumulate my j-half for MY tile, then partner's tile
                const double* w3a = &WL[oW3L + (Town * 16 + h * 32 / 32 * 32)];
                // base for (row = Town*8 + k2, jh = h):
                //   offset = ((Town*8+k2)*2 + h)*32 = Town*512 + h*32 + k2*64
                const double* wa = &WL[oW3L + Town * 512 + h * 32];
                #pragma unroll
                for (int k2 = 0; k2 < 8; ++k2) {
                    #pragma unroll
                    for (int j = 0; j < 32; ++j)
                        acc3[j] = fma(wa[k2 * 64 + j], h2t[k2], acc3[j]);
                }
                const double* wp = &WL[oW3L + Tpar * 512 + h * 32];
                #pragma unroll
                for (int k2 = 0; k2 < 8; ++k2) {
                    #pragma unroll
                    for (int j = 0; j < 32; ++j)
                        acc3[j] = fma(wp[k2 * 64 + j], rcv[k2], acc3[j]);
                }
                (void)w3a;
            }

            // ---- L4: 64 -> 3, my j-half then pairwise combine ----
            double e0 = (h == 0) ? WL[oB4 + 0] : 0.0;
            double e1 = (h == 0) ? WL[oB4 + 1] : 0.0;
            double e2 = (h == 0) ? WL[oB4 + 2] : 0.0;
            #pragma unroll
            for (int j = 0; j < 32; ++j) {
                double ht = (double)tanhf((float)acc3[j]);
                const double* w4 = &WL[oW4 + (h * 32 + j) * 3];
                e0 = fma(w4[0], ht, e0);
                e1 = fma(w4[1], ht, e1);
                e2 = fma(w4[2], ht, e2);
            }
            // both lanes end with the identical full sum (a+b == b+a exactly)
            e0 += __shfl_xor(e0, 1);
            e1 += __shfl_xor(e1, 1);
            e2 += __shfl_xor(e2, 1);

            double w = (st == 1 || st == 2) ? 2.0 : 1.0;
            ks0 = fma(w, e0, ks0);
            ks1 = fma(w, e1, ks1);
            ks2 = fma(w, e2, ks2);
            double a = (st < 2) ? 0.5 * dt : dt;
            zs = fma(a, e0, ys);
            zi = fma(a, e1, yi);
            zr = fma(a, e2, yr);
        }

        double c6 = dt * (1.0 / 6.0);
        ys = fma(c6, ks0, ys);
        yi = fma(c6, ks1, yi);
        yr = fma(c6, ks2, yr);

        if (h == 0)
            store_softmax(out, ((size_t)(t + 1) * B + traj) * 3,
                          (float)ys, (float)yi, (float)yr);
    }
}

// widen all params to f64 in ws with the kernel's LDS layout
__global__ void stage_params_kernel(
    const float* __restrict__ W1, const float* __restrict__ b1,
    const float* __restrict__ W2, const float* __restrict__ b2,
    const float* __restrict__ W3, const float* __restrict__ b3,
    const float* __restrict__ W4, const float* __restrict__ b4,
    double* __restrict__ P)
{
    int idx = blockIdx.x * blockDim.x + threadIdx.x;
    if (idx >= NTOT) return;
    float v;
    if (idx < oB1)       { int u = idx - oW1T; v = W1[(u % 5) * 64 + (u / 5)]; }
    else if (idx < oW2L) v = b1[idx - oB1];
    else if (idx < oB2)  { int u = idx - oW2L; int c = u >> 9; int i = (u >> 3) & 63; int q = u & 7;
                           v = W2[i * 128 + c * 8 + q]; }
    else if (idx < oW3L) v = b2[idx - oB2];
    else if (idx < oB3)  { int u = idx - oW3L; int g = u >> 5; int jq = u & 31;
                           v = W3[(g >> 1) * 64 + (g & 1) * 32 + jq]; }
    else if (idx < oW4)  v = b3[idx - oB3];
    else if (idx < oB4)  v = W4[idx - oW4];
    else                 v = b4[idx - oB4];
    P[idx] = (double)v;
}

extern "C" void kernel_launch(void* const* d_in, const int* in_sizes, int n_in,
                              void* d_out, int out_size, void* d_ws, size_t ws_size,
                              hipStream_t stream) {
    const float* y0    = (const float*)d_in[0];
    const float* tspan = (const float*)d_in[1];
    const float* beta  = (const float*)d_in[2];
    const float* gamma = (const float*)d_in[3];
    const float* W1    = (const float*)d_in[4];
    const float* b1    = (const float*)d_in[5];
    const float* W2    = (const float*)d_in[6];
    const float* b2    = (const float*)d_in[7];
    const float* W3    = (const float*)d_in[8];
    const float* b3    = (const float*)d_in[9];
    const float* W4    = (const float*)d_in[10];
    const float* b4    = (const float*)d_in[11];

    int B = in_sizes[0] / 3;
    int T = in_sizes[1];
    float* out = (float*)d_out;

    double* P = (double*)d_ws;
    stage_params_kernel<<<(NTOT + 255) / 256, 256, 0, stream>>>(
        W1, b1, W2, b2, W3, b3, W4, b4, P);

    // allow >64KB dynamic LDS (host-side attribute; idempotent; r7-proven
    // to be graph-capture safe)
    hipFuncSetAttribute((const void*)sir_rk4_kernel,
                        hipFuncAttributeMaxDynamicSharedMemorySize, LDS_BYTES);

    int threads_total = 2 * B;                       // 2 lanes per trajectory
    int blocks = (threads_total + 511) / 512;        // 512
    sir_rk4_kernel<<<blocks, 512, LDS_BYTES, stream>>>(
        y0, tspan, beta, gamma, P, out, B, T);
}

// Round 10
// 615891.797 us; speedup vs baseline: 3.9075x; 3.9075x over previous
//
#include <hip/hip_runtime.h>

// NeuralODESIR round 10: lane-pair split, all constraints from r6-r9 honored:
//  (1) f64 MACs (precision floor, r2-r5); (2) accumulators in VGPRs (r6's
//  AGPR-RMW tax ~5 ops/MAC); (3) h1 in LDS (r7/r9: h1-in-regs + unrolled LDS
//  consumers -> hoisting -> spill -> 40x); (4) weights f64 (r8: cvt-per-MAC
//  tax); (5) weight loads LANE-DIVERGENT so they stay VMEM global_load
//  (r8 datum: uniform addresses get scalarized to s_load -> SMEM stall).
// Topology: 2 lanes per trajectory. Lane h owns k-tiles h*8..h*8+7 (8 dbl
// wide) and acc3 j-half h*32..h*32+31 (f64[32] = 64 VGPR). h2 tile exchanged
// via shfl_xor(.,1); L4 partials shfl-added (bit-exact, r9-proven numerics).
// Explicit named VMEM ping-pong buffers, statically indexed (rule #20).

#define oW1T 0          // [64][5]   W1 transposed (SMEM path, K$-resident)
#define oB1  320        // [64]
#define oW2L 384        // [16 tiles][64 i][8 q] : W2L[T*512+i*8+q] = W2[i*128+T*8+q]
#define oB2  8576       // [128] natural
#define oW3  8704       // [128][64] natural
#define oB3  16896      // [64]
#define oW4  16960      // [64][3] natural
#define oB4  17152      // [3]
#define NTOT 17155

#define LOAD8(D, S) do { \
    const double2* p_ = (const double2*)(S); \
    double2 a0_ = p_[0], a1_ = p_[1], a2_ = p_[2], a3_ = p_[3]; \
    D[0]=a0_.x; D[1]=a0_.y; D[2]=a1_.x; D[3]=a1_.y; \
    D[4]=a2_.x; D[5]=a2_.y; D[6]=a3_.x; D[7]=a3_.y; } while(0)

__device__ __forceinline__ void store_softmax(float* __restrict__ out, size_t base,
                                              float a, float b, float c) {
    float m  = fmaxf(a, fmaxf(b, c));
    float e0 = expf(a - m);
    float e1 = expf(b - m);
    float e2 = expf(c - m);
    float s  = e0 + e1 + e2;
    out[base + 0] = e0 / s;
    out[base + 1] = e1 / s;
    out[base + 2] = e2 / s;
}

__global__ __launch_bounds__(256, 2) void sir_rk4_kernel(
    const float* __restrict__ y0,   const float* __restrict__ tspan,
    const float* __restrict__ beta, const float* __restrict__ gamma,
    const double* __restrict__ P,
    float* __restrict__ out, int B, int T)
{
    // h1 staging: [elem][traj_local]; lane pairs read same address (free),
    // consecutive trajs -> consecutive banks. Same-wave write->read needs no
    // barrier (single instruction stream + compiler lgkmcnt).
    __shared__ float hbuf[64][128];

    const int tid  = threadIdx.x;
    const int m    = tid >> 1;                 // local trajectory 0..127
    const int h    = tid & 1;                  // half index
    const int traj = blockIdx.x * 128 + m;
    if (traj >= B) return;

    const double* W1T = P + oW1T;              // wave-uniform -> SMEM, K$-resident
    const double* B1v = P + oB1;

    double ys = (double)y0[traj * 3 + 0];
    double yi = (double)y0[traj * 3 + 1];
    double yr = (double)y0[traj * 3 + 2];
    const double be = (double)beta[traj];
    const double ga = (double)gamma[traj];

    if (h == 0)
        store_softmax(out, (size_t)traj * 3, (float)ys, (float)yi, (float)yr);

    #pragma unroll 1
    for (int t = 0; t < T - 1; ++t) {
        double dt = (double)tspan[t + 1] - (double)tspan[t];

        double ks0 = 0.0, ks1 = 0.0, ks2 = 0.0;
        double zs = ys, zi = yi, zr = yr;

        #pragma unroll 1
        for (int st = 0; st < 4; ++st) {
            // ---- L1: 5 -> 64. Both lanes compute all 64 (dup +4% FLOP) so
            // weights stay wave-uniform (SMEM). Both write same value: benign.
            #pragma unroll 2
            for (int j = 0; j < 64; ++j) {
                const double* w = W1T + j * 5;
                double ta = fma(w[0], zs, B1v[j]);
                double tb = w[2] * zr;
                ta = fma(w[1], zi, ta);
                tb = fma(w[3], be, tb);
                ta = fma(w[4], ga, ta);
                hbuf[j][m] = tanhf((float)(ta + tb));
            }

            // my half of the L3 accumulators, in VGPRs
            double acc3[32];
            {
                const double* b3p = P + oB3 + h * 32;   // lane-divergent -> VMEM
                #pragma unroll
                for (int j = 0; j < 32; ++j) acc3[j] = b3p[j];
            }

            // ---- L2+L3: 64 -> 128 -> 64, pair-split, 8 tile-iterations ----
            #pragma unroll 1
            for (int cl = 0; cl < 8; ++cl) {
                const int Town = h * 8 + cl;           // my k-tile
                const int Tpar = Town ^ 8;             // partner's k-tile

                // L2: h2t[q] = b2[T*8+q] + sum_i W2[i][T*8+q] * h1[i]
                double h2t[8];
                LOAD8(h2t, P + oB2 + Town * 8);        // lane-divergent VMEM

                const double* wb = P + oW2L + (size_t)Town * 512;
                double w0[8], w1[8], w2[8], w3r[8];    // named rotation (static idx)
                LOAD8(w0, wb + 0 * 8);
                LOAD8(w1, wb + 1 * 8);
                #pragma unroll 1
                for (int i = 0; i < 64; i += 4) {
                    LOAD8(w2, wb + (size_t)(i + 2) * 8);
                    {
                        double hv = (double)hbuf[i][m];
                        #pragma unroll
                        for (int q = 0; q < 8; ++q) h2t[q] = fma(w0[q], hv, h2t[q]);
                    }
                    LOAD8(w3r, wb + (size_t)(i + 3) * 8);
                    {
                        double hv = (double)hbuf[i + 1][m];
                        #pragma unroll
                        for (int q = 0; q < 8; ++q) h2t[q] = fma(w1[q], hv, h2t[q]);
                    }
                    // rows 64/65 overflow into the B2 region: in-bounds, unused
                    LOAD8(w0, wb + (size_t)(i + 4) * 8);
                    {
                        double hv = (double)hbuf[i + 2][m];
                        #pragma unroll
                        for (int q = 0; q < 8; ++q) h2t[q] = fma(w2[q], hv, h2t[q]);
                    }
                    LOAD8(w1, wb + (size_t)(i + 5) * 8);
                    {
                        double hv = (double)hbuf[i + 3][m];
                        #pragma unroll
                        for (int q = 0; q < 8; ++q) h2t[q] = fma(w3r[q], hv, h2t[q]);
                    }
                }

                #pragma unroll
                for (int q = 0; q < 8; ++q)
                    h2t[q] = (double)tanhf((float)h2t[q]);

                // exchange tile activations with partner lane
                double rcv[8];
                #pragma unroll
                for (int q = 0; q < 8; ++q) rcv[q] = __shfl_xor(h2t[q], 1);

                // L3: 16 rows (8 own + 8 partner) x my 32-j half, as 64
                // chunks of 8, 4-buffer rotation prefetched 3 ahead.
                const double* w3o = P + oW3 + (size_t)Town * 8 * 64 + h * 32;
                const double* w3p = P + oW3 + (size_t)Tpar * 8 * 64 + h * 32;
                double uu[4][8];
                LOAD8(uu[0], w3o + 0 * 64 + 0 * 8);
                LOAD8(uu[1], w3o + 0 * 64 + 1 * 8);
                LOAD8(uu[2], w3o + 0 * 64 + 2 * 8);
                #pragma unroll
                for (int idx = 0; idx < 64; ++idx) {
                    const int nx = idx + 3;
                    if (nx < 64) {     // static under full unroll
                        const double* nsrc = (nx < 32)
                            ? (w3o + (size_t)(nx >> 2) * 64 + (size_t)(nx & 3) * 8)
                            : (w3p + (size_t)((nx - 32) >> 2) * 64 + (size_t)(nx & 3) * 8);
                        LOAD8(uu[nx & 3], nsrc);
                    }
                    const double hv = (idx < 32) ? h2t[idx >> 2] : rcv[(idx - 32) >> 2];
                    #pragma unroll
                    for (int q = 0; q < 8; ++q)
                        acc3[(idx & 3) * 8 + q] = fma(uu[idx & 3][q], hv, acc3[(idx & 3) * 8 + q]);
                }
            }

            // ---- L4: 64 -> 3 on my j-half, then pairwise combine ----
            double e0 = (h == 0) ? P[oB4 + 0] : 0.0;
            double e1 = (h == 0) ? P[oB4 + 1] : 0.0;
            double e2 = (h == 0) ? P[oB4 + 2] : 0.0;
            {
                const double* w4 = P + oW4 + (size_t)(h * 32) * 3;  // lane-divergent
                #pragma unroll 4
                for (int j = 0; j < 32; ++j) {
                    double ht = (double)tanhf((float)acc3[j]);
                    e0 = fma(w4[j * 3 + 0], ht, e0);
                    e1 = fma(w4[j * 3 + 1], ht, e1);
                    e2 = fma(w4[j * 3 + 2], ht, e2);
                }
            }
            e0 += __shfl_xor(e0, 1);   // a+b == b+a exactly: lanes stay identical
            e1 += __shfl_xor(e1, 1);
            e2 += __shfl_xor(e2, 1);

            double w = (st == 1 || st == 2) ? 2.0 : 1.0;
            ks0 = fma(w, e0, ks0);
            ks1 = fma(w, e1, ks1);
            ks2 = fma(w, e2, ks2);
            double a = (st < 2) ? 0.5 * dt : dt;
            zs = fma(a, e0, ys);
            zi = fma(a, e1, yi);
            zr = fma(a, e2, yr);
        }

        double c6 = dt * (1.0 / 6.0);
        ys = fma(c6, ks0, ys);
        yi = fma(c6, ks1, yi);
        yr = fma(c6, ks2, yr);

        if (h == 0)
            store_softmax(out, ((size_t)(t + 1) * B + traj) * 3,
                          (float)ys, (float)yi, (float)yr);
    }
}

// widen all params to f64 in ws with the kernel's layout
__global__ void stage_params_kernel(
    const float* __restrict__ W1, const float* __restrict__ b1,
    const float* __restrict__ W2, const float* __restrict__ b2,
    const float* __restrict__ W3, const float* __restrict__ b3,
    const float* __restrict__ W4, const float* __restrict__ b4,
    double* __restrict__ P)
{
    int idx = blockIdx.x * blockDim.x + threadIdx.x;
    if (idx >= NTOT) return;
    float v;
    if (idx < oB1)       { int u = idx - oW1T; v = W1[(u % 5) * 64 + (u / 5)]; }
    else if (idx < oW2L) v = b1[idx - oB1];
    else if (idx < oB2)  { int u = idx - oW2L; int Tt = u >> 9; int i = (u >> 3) & 63; int q = u & 7;
                           v = W2[i * 128 + Tt * 8 + q]; }
    else if (idx < oW3)  v = b2[idx - oB2];
    else if (idx < oB3)  v = W3[idx - oW3];
    else if (idx < oW4)  v = b3[idx - oB3];
    else if (idx < oB4)  v = W4[idx - oW4];
    else                 v = b4[idx - oB4];
    P[idx] = (double)v;
}

extern "C" void kernel_launch(void* const* d_in, const int* in_sizes, int n_in,
                              void* d_out, int out_size, void* d_ws, size_t ws_size,
                              hipStream_t stream) {
    const float* y0    = (const float*)d_in[0];
    const float* tspan = (const float*)d_in[1];
    const float* beta  = (const float*)d_in[2];
    const float* gamma = (const float*)d_in[3];
    const float* W1    = (const float*)d_in[4];
    const float* b1    = (const float*)d_in[5];
    const float* W2    = (const float*)d_in[6];
    const float* b2    = (const float*)d_in[7];
    const float* W3    = (const float*)d_in[8];
    const float* b3    = (const float*)d_in[9];
    const float* W4    = (const float*)d_in[10];
    const float* b4    = (const float*)d_in[11];

    int B = in_sizes[0] / 3;
    int T = in_sizes[1];
    float* out = (float*)d_out;

    double* P = (double*)d_ws;
    stage_params_kernel<<<(NTOT + 255) / 256, 256, 0, stream>>>(
        W1, b1, W2, b2, W3, b3, W4, b4, P);

    int threads_total = 2 * B;                 // 2 lanes per trajectory
    int blocks = (threads_total + 255) / 256;  // 1024
    sir_rk4_kernel<<<blocks, 256, 0, stream>>>(
        y0, tspan, beta, gamma, P, out, B, T);
}